// Round 1
// baseline (1206.359 us; speedup 1.0000x reference)
//
#include <hip/hip_runtime.h>
#include <hip/hip_bf16.h>

#define N_NODES 50000
#define IN_F 256
#define HIDD 16
#define HEADS 4
#define TT 2
#define EDG 800000
#define OUTF 16
#define SLOPE 0.2f

__device__ __forceinline__ float lrelu(float x) { return x >= 0.f ? x : SLOPE * x; }

// ---------------------------------------------------------------------------
// Fused GEMM (both edge types) + el/er epilogue.
// h_t = X @ W_t  [N,64];  el_t[n,head] = sum_d h*al;  er likewise.
// Block: 256 threads, tile 64 rows x 64 cols (full width), k-tile 64.
// Thread tile: 4 rows x 4 cols per type (32 fp32 accumulators).
// ---------------------------------------------------------------------------
__global__ __launch_bounds__(256) void gemm_el_er(
    const float* __restrict__ X, const float* __restrict__ W,
    const float* __restrict__ al, const float* __restrict__ ar,
    float* __restrict__ h, float* __restrict__ el, float* __restrict__ er) {
  __shared__ float Xs[64][65];
  __shared__ float Ws[2][64][64];
  const int tid = threadIdx.x;
  const int n0 = blockIdx.x * 64;
  const int rq = tid >> 4;   // 0..15 -> rows rq*4..+3
  const int cb = tid & 15;   // 0..15 -> cols cb*4..+3
  float4 acc0[4], acc1[4];
#pragma unroll
  for (int r = 0; r < 4; ++r) {
    acc0[r] = make_float4(0.f, 0.f, 0.f, 0.f);
    acc1[r] = make_float4(0.f, 0.f, 0.f, 0.f);
  }
  for (int k0 = 0; k0 < IN_F; k0 += 64) {
#pragma unroll
    for (int i = 0; i < 16; ++i) {
      int L = i * 256 + tid;
      int r = L >> 6, c = L & 63;
      int gr = n0 + r;
      Xs[r][c] = (gr < N_NODES) ? X[(size_t)gr * IN_F + k0 + c] : 0.f;
      Ws[0][r][c] = W[(size_t)(k0 + r) * 64 + c];
      Ws[1][r][c] = W[(size_t)IN_F * 64 + (size_t)(k0 + r) * 64 + c];
    }
    __syncthreads();
#pragma unroll 8
    for (int k = 0; k < 64; ++k) {
      const float4 w0 = *(const float4*)&Ws[0][k][cb * 4];
      const float4 w1 = *(const float4*)&Ws[1][k][cb * 4];
#pragma unroll
      for (int rr = 0; rr < 4; ++rr) {
        float x = Xs[rq * 4 + rr][k];
        acc0[rr].x += x * w0.x; acc0[rr].y += x * w0.y;
        acc0[rr].z += x * w0.z; acc0[rr].w += x * w0.w;
        acc1[rr].x += x * w1.x; acc1[rr].y += x * w1.y;
        acc1[rr].z += x * w1.z; acc1[rr].w += x * w1.w;
      }
    }
    __syncthreads();
  }
  const int head = cb >> 2, q = cb & 3;
  // attention vectors for this thread's 4 dims (q*4..q*4+3) of its head
  const float4 al0 = *(const float4*)&al[head * 16 + q * 4];
  const float4 ar0 = *(const float4*)&ar[head * 16 + q * 4];
  const float4 al1 = *(const float4*)&al[64 + head * 16 + q * 4];
  const float4 ar1 = *(const float4*)&ar[64 + head * 16 + q * 4];
#pragma unroll
  for (int rr = 0; rr < 4; ++rr) {
    int gr = n0 + rq * 4 + rr;
    float pl0 = acc0[rr].x * al0.x + acc0[rr].y * al0.y + acc0[rr].z * al0.z + acc0[rr].w * al0.w;
    float pr0 = acc0[rr].x * ar0.x + acc0[rr].y * ar0.y + acc0[rr].z * ar0.z + acc0[rr].w * ar0.w;
    float pl1 = acc1[rr].x * al1.x + acc1[rr].y * al1.y + acc1[rr].z * al1.z + acc1[rr].w * al1.w;
    float pr1 = acc1[rr].x * ar1.x + acc1[rr].y * ar1.y + acc1[rr].z * ar1.z + acc1[rr].w * ar1.w;
    // reduce over the 4 q-lanes (lane bits 0,1)
    pl0 += __shfl_xor(pl0, 1); pl0 += __shfl_xor(pl0, 2);
    pr0 += __shfl_xor(pr0, 1); pr0 += __shfl_xor(pr0, 2);
    pl1 += __shfl_xor(pl1, 1); pl1 += __shfl_xor(pl1, 2);
    pr1 += __shfl_xor(pr1, 1); pr1 += __shfl_xor(pr1, 2);
    if (gr < N_NODES) {
      *(float4*)&h[(size_t)gr * 64 + cb * 4] = acc0[rr];
      *(float4*)&h[(size_t)N_NODES * 64 + (size_t)gr * 64 + cb * 4] = acc1[rr];
      if (q == 0) {
        el[(size_t)gr * 4 + head] = pl0;
        er[(size_t)gr * 4 + head] = pr0;
        el[(size_t)N_NODES * 4 + (size_t)gr * 4 + head] = pl1;
        er[(size_t)N_NODES * 4 + (size_t)gr * 4 + head] = pr1;
      }
    }
  }
}

// ---------------------------------------------------------------------------
// CSR construction: histogram -> scan -> scatter
// ---------------------------------------------------------------------------
__global__ void count_kernel(const int* __restrict__ dst, int* __restrict__ cnt) {
  const int t = blockIdx.y;
  const int* d = dst + (size_t)t * EDG;
  int* c = cnt + (size_t)t * N_NODES;
  for (int i = blockIdx.x * blockDim.x + threadIdx.x; i < EDG; i += gridDim.x * blockDim.x)
    atomicAdd(&c[d[i]], 1);
}

__global__ __launch_bounds__(1024) void scan_kernel(
    const int* __restrict__ cnt, int* __restrict__ offs, int* __restrict__ cursor) {
  const int t = blockIdx.x;
  const int n = N_NODES;
  const int* c = cnt + (size_t)t * n;
  int* o = offs + (size_t)t * (n + 1);
  int* cur = cursor + (size_t)t * n;
  const int tid = threadIdx.x;
  const int run = (n + 1023) / 1024;  // 49
  const int base = tid * run;
  const int end = min(base + run, n);
  int s = 0;
  for (int i = base; i < end; ++i) s += c[i];
  const int lane = tid & 63, wave = tid >> 6;
  int v = s;
#pragma unroll
  for (int d = 1; d < 64; d <<= 1) {
    int x = __shfl_up(v, d, 64);
    if (lane >= d) v += x;
  }
  __shared__ int wsum[16];
  if (lane == 63) wsum[wave] = v;
  __syncthreads();
  if (wave == 0 && lane < 16) {
    int wv = wsum[lane];
#pragma unroll
    for (int d = 1; d < 16; d <<= 1) {
      int x = __shfl_up(wv, d, 64);
      if (lane >= d) wv += x;
    }
    wsum[lane] = wv;  // inclusive wave sums
  }
  __syncthreads();
  const int waveoff = (wave == 0) ? 0 : wsum[wave - 1];
  int p = waveoff + v - s;  // exclusive prefix for this thread
  for (int i = base; i < end; ++i) {
    o[i] = p; cur[i] = p; p += c[i];
  }
  if (tid == 1023) o[n] = p;  // grand total
}

__global__ void scatter_kernel(const int* __restrict__ src, const int* __restrict__ dst,
                               int* __restrict__ cursor, int* __restrict__ srcS) {
  const int t = blockIdx.y;
  const int* s = src + (size_t)t * EDG;
  const int* d = dst + (size_t)t * EDG;
  int* cur = cursor + (size_t)t * N_NODES;
  int* out = srcS + (size_t)t * EDG;
  for (int i = blockIdx.x * blockDim.x + threadIdx.x; i < EDG; i += gridDim.x * blockDim.x) {
    int dd = d[i];
    int pos = atomicAdd(&cur[dd], 1);
    out[pos] = s[i];
  }
}

// ---------------------------------------------------------------------------
// Per-node softmax + aggregation: one wave per node, lane = head*16 + dim.
// Self-loop always included. Two passes over the node's CSR edge list.
// ---------------------------------------------------------------------------
__global__ __launch_bounds__(256) void aggregate_kernel(
    const float* __restrict__ h, const float* __restrict__ el, const float* __restrict__ er,
    const int* __restrict__ offs, const int* __restrict__ srcS,
    const float* __restrict__ bias, float* __restrict__ rst) {
  const int t = blockIdx.y;
  const int node = blockIdx.x * 4 + (threadIdx.x >> 6);
  const int lane = threadIdx.x & 63;
  if (node >= N_NODES) return;
  const float* ht = h + (size_t)t * N_NODES * 64;
  const float* elt = el + (size_t)t * N_NODES * 4;
  const float* ert = er + (size_t)t * N_NODES * 4;
  const int* ot = offs + (size_t)t * (N_NODES + 1);
  const int* st = srcS + (size_t)t * EDG;
  const int head = lane >> 4;
  const float ern = ert[node * 4 + head];
  const int beg = ot[node], end = ot[node + 1];
  float eself = lrelu(elt[node * 4 + head] + ern);
  float m = eself;
  for (int j = beg; j < end; ++j) {
    int s = st[j];
    m = fmaxf(m, lrelu(elt[s * 4 + head] + ern));
  }
  float p = __expf(eself - m);
  float denom = p;
  float acc = p * ht[(size_t)node * 64 + lane];
  for (int j = beg; j < end; ++j) {
    int s = st[j];
    float pe = __expf(lrelu(elt[s * 4 + head] + ern) - m);
    denom += pe;
    acc += pe * ht[(size_t)s * 64 + lane];
  }
  rst[(size_t)t * N_NODES * 64 + (size_t)node * 64 + lane] = acc / denom + bias[t * 64 + lane];
}

// ---------------------------------------------------------------------------
// Final projection: out[o] = sum_i rst_flat[i] * Wout[o, i] + bout[o]
// ---------------------------------------------------------------------------
__global__ __launch_bounds__(256) void dot_kernel(
    const float* __restrict__ rst, const float* __restrict__ Wout,
    const float* __restrict__ bout, float* __restrict__ out) {
  const int nf4 = (TT * N_NODES * 64) / 4;  // 1,600,000
  float acc[16];
#pragma unroll
  for (int o = 0; o < 16; ++o) acc[o] = 0.f;
  const float4* hv = (const float4*)rst;
  const float4* wv = (const float4*)Wout;
  for (int i = blockIdx.x * blockDim.x + threadIdx.x; i < nf4; i += gridDim.x * blockDim.x) {
    float4 h4 = hv[i];
#pragma unroll
    for (int o = 0; o < 16; ++o) {
      float4 w4 = wv[(size_t)o * nf4 + i];
      acc[o] += h4.x * w4.x + h4.y * w4.y + h4.z * w4.z + h4.w * w4.w;
    }
  }
#pragma unroll
  for (int o = 0; o < 16; ++o) {
#pragma unroll
    for (int d = 1; d < 64; d <<= 1) acc[o] += __shfl_xor(acc[o], d);
  }
  __shared__ float part[4][16];
  const int w = threadIdx.x >> 6, lane = threadIdx.x & 63;
  if (lane == 0) {
#pragma unroll
    for (int o = 0; o < 16; ++o) part[w][o] = acc[o];
  }
  __syncthreads();
  if (threadIdx.x < 16) {
    float s = part[0][threadIdx.x] + part[1][threadIdx.x] +
              part[2][threadIdx.x] + part[3][threadIdx.x];
    if (blockIdx.x == 0) s += bout[threadIdx.x];
    atomicAdd(&out[threadIdx.x], s);
  }
}

extern "C" void kernel_launch(void* const* d_in, const int* in_sizes, int n_in,
                              void* d_out, int out_size, void* d_ws, size_t ws_size,
                              hipStream_t stream) {
  const float* node_feat = (const float*)d_in[0];
  const int*   src       = (const int*)d_in[1];
  const int*   dst       = (const int*)d_in[2];
  const float* W         = (const float*)d_in[3];
  const float* attn_l    = (const float*)d_in[4];
  const float* attn_r    = (const float*)d_in[5];
  const float* bias_conv = (const float*)d_in[6];
  const float* W_out     = (const float*)d_in[7];
  const float* b_out     = (const float*)d_in[8];
  float* out = (float*)d_out;

  // workspace layout (all 16B aligned)
  float* h   = (float*)d_ws;                              // TT*N*64
  float* rst = h + (size_t)TT * N_NODES * 64;             // TT*N*64
  float* el  = rst + (size_t)TT * N_NODES * 64;           // TT*N*4
  float* er  = el + (size_t)TT * N_NODES * 4;             // TT*N*4
  int* cnt    = (int*)(er + (size_t)TT * N_NODES * 4);    // TT*N
  int* offs   = cnt + TT * N_NODES;                       // TT*(N+1)
  int* cursor = offs + TT * (N_NODES + 1);                // TT*N
  int* srcS   = cursor + TT * N_NODES;                    // TT*E

  hipMemsetAsync(cnt, 0, (size_t)TT * N_NODES * sizeof(int), stream);
  hipMemsetAsync(out, 0, OUTF * sizeof(float), stream);

  gemm_el_er<<<dim3((N_NODES + 63) / 64), 256, 0, stream>>>(node_feat, W, attn_l, attn_r, h, el, er);
  count_kernel<<<dim3(1024, TT), 256, 0, stream>>>(dst, cnt);
  scan_kernel<<<dim3(TT), 1024, 0, stream>>>(cnt, offs, cursor);
  scatter_kernel<<<dim3(1024, TT), 256, 0, stream>>>(src, dst, cursor, srcS);
  aggregate_kernel<<<dim3(N_NODES / 4, TT), 256, 0, stream>>>(h, el, er, offs, srcS, bias_conv, rst);
  dot_kernel<<<1024, 256, 0, stream>>>(rst, W_out, b_out, out);
}